// Round 1
// baseline (2119.009 us; speedup 1.0000x reference)
//
#include <hip/hip_runtime.h>
#include <math.h>

#define B_  256
#define T_  512
#define D_  256
#define A_  50
#define AP  52      // A padded to multiple of 4
#define EPS 1e-7f

// ---------------------------------------------------------------------------
// Kernel 1: per-row scores  s[b,t] = exp( sum_a tanh( x[b,t,:]·W[:,a] + b[a] ) * u[a] )
// One block per batch b (256 blocks, 256 threads). Each thread owns rows
// t = tid and t = tid + 256. W (zero-padded to 52 cols) lives in LDS and is
// read via broadcast ds_read_b128 (wave-uniform address -> no bank conflicts).
// Also block-reduces sum_t s[b,t] into sums[b].
// ---------------------------------------------------------------------------
__global__ __launch_bounds__(256, 2)
void scores_kernel(const float* __restrict__ x, const float* __restrict__ W,
                   const float* __restrict__ bias, const float* __restrict__ u,
                   float* __restrict__ s_out, float* __restrict__ sums)
{
    __shared__ float W_lds[D_ * AP];
    __shared__ float b_lds[AP];
    __shared__ float u_lds[AP];
    __shared__ float red[256];

    const int tid = threadIdx.x;
    const int bb  = blockIdx.x;

    // Stage W (zero-padded) into LDS
    for (int idx = tid; idx < D_ * AP; idx += 256) {
        int d = idx / AP;
        int a = idx - d * AP;
        W_lds[idx] = (a < A_) ? W[d * A_ + a] : 0.0f;
    }
    if (tid < AP) {
        b_lds[tid] = (tid < A_) ? bias[tid] : 0.0f;
        u_lds[tid] = (tid < A_) ? u[tid]    : 0.0f;
    }
    __syncthreads();

    const float* __restrict__ x0 = x + ((size_t)bb * T_ + tid) * D_;
    const float* __restrict__ x1 = x0 + 256 * D_;

    float acc0[AP], acc1[AP];
    #pragma unroll
    for (int a = 0; a < AP; a++) { acc0[a] = 0.0f; acc1[a] = 0.0f; }

    // K-loop over d in chunks of 4, software prefetch one chunk ahead
    float4 c0 = *(const float4*)(x0);
    float4 c1 = *(const float4*)(x1);

    auto compute_chunk = [&](float4 v0, float4 v1, int d4) {
        const float xr0[4] = {v0.x, v0.y, v0.z, v0.w};
        const float xr1[4] = {v1.x, v1.y, v1.z, v1.w};
        #pragma unroll
        for (int j = 0; j < 4; j++) {
            const int d = d4 * 4 + j;
            const float4* __restrict__ Wrow = (const float4*)(&W_lds[d * AP]);
            #pragma unroll
            for (int a4 = 0; a4 < AP / 4; a4++) {
                float4 w = Wrow[a4];
                acc0[a4 * 4 + 0] += xr0[j] * w.x;
                acc0[a4 * 4 + 1] += xr0[j] * w.y;
                acc0[a4 * 4 + 2] += xr0[j] * w.z;
                acc0[a4 * 4 + 3] += xr0[j] * w.w;
                acc1[a4 * 4 + 0] += xr1[j] * w.x;
                acc1[a4 * 4 + 1] += xr1[j] * w.y;
                acc1[a4 * 4 + 2] += xr1[j] * w.z;
                acc1[a4 * 4 + 3] += xr1[j] * w.w;
            }
        }
    };

    for (int d4 = 0; d4 < D_ / 4 - 1; d4++) {
        float4 n0 = *(const float4*)(x0 + (d4 + 1) * 4);
        float4 n1 = *(const float4*)(x1 + (d4 + 1) * 4);
        compute_chunk(c0, c1, d4);
        c0 = n0; c1 = n1;
    }
    compute_chunk(c0, c1, D_ / 4 - 1);

    // tanh + dot with u
    float sc0 = 0.0f, sc1 = 0.0f;
    #pragma unroll
    for (int a = 0; a < AP; a++) {
        sc0 += tanhf(acc0[a] + b_lds[a]) * u_lds[a];
        sc1 += tanhf(acc1[a] + b_lds[a]) * u_lds[a];
    }
    float s0 = expf(sc0);
    float s1 = expf(sc1);

    s_out[(size_t)bb * T_ + tid]       = s0;
    s_out[(size_t)bb * T_ + 256 + tid] = s1;

    // block-reduce sum of exp scores
    red[tid] = s0 + s1;
    __syncthreads();
    for (int off = 128; off > 0; off >>= 1) {
        if (tid < off) red[tid] += red[tid + off];
        __syncthreads();
    }
    if (tid == 0) sums[bb] = red[0];
}

// ---------------------------------------------------------------------------
// Kernel 2: out[b,d] = sum_t x[b,t,d] * s[b,t] / (sums[b] + EPS)
// One block per batch. Wave w handles t in [w*128,(w+1)*128); lane l owns
// float4 d-chunk l (64 lanes * 4 = 256 = D). Perfectly coalesced 1KB/wave
// global loads. Cross-wave combine through LDS.
// ---------------------------------------------------------------------------
__global__ __launch_bounds__(256, 2)
void pool_kernel(const float* __restrict__ x, const float* __restrict__ s_in,
                 const float* __restrict__ sums, float* __restrict__ out)
{
    __shared__ float s_lds[T_];
    __shared__ float part[4 * 256];

    const int tid = threadIdx.x;
    const int bb  = blockIdx.x;

    const float inv = 1.0f / (sums[bb] + EPS);
    s_lds[tid]       = s_in[(size_t)bb * T_ + tid]       * inv;
    s_lds[tid + 256] = s_in[(size_t)bb * T_ + 256 + tid] * inv;
    __syncthreads();

    const int w = tid >> 6;   // wave id 0..3
    const int l = tid & 63;   // lane

    const float* __restrict__ xb = x + (size_t)bb * T_ * D_;
    float4 acc = make_float4(0.f, 0.f, 0.f, 0.f);

    const int t0 = w * (T_ / 4);
    #pragma unroll 4
    for (int t = t0; t < t0 + T_ / 4; t++) {
        float4 xv = *(const float4*)(xb + (size_t)t * D_ + l * 4);
        float sv  = s_lds[t];
        acc.x += xv.x * sv;
        acc.y += xv.y * sv;
        acc.z += xv.z * sv;
        acc.w += xv.w * sv;
    }

    part[w * 256 + l * 4 + 0] = acc.x;
    part[w * 256 + l * 4 + 1] = acc.y;
    part[w * 256 + l * 4 + 2] = acc.z;
    part[w * 256 + l * 4 + 3] = acc.w;
    __syncthreads();

    float o = part[tid] + part[256 + tid] + part[512 + tid] + part[768 + tid];
    out[(size_t)bb * D_ + tid] = o;
}

// ---------------------------------------------------------------------------
extern "C" void kernel_launch(void* const* d_in, const int* in_sizes, int n_in,
                              void* d_out, int out_size, void* d_ws, size_t ws_size,
                              hipStream_t stream)
{
    const float* x = (const float*)d_in[0];
    const float* W = (const float*)d_in[1];
    const float* b = (const float*)d_in[2];
    const float* u = (const float*)d_in[3];

    float* scores = (float*)d_ws;              // B*T floats
    float* sums   = scores + (size_t)B_ * T_;  // B floats
    float* out    = (float*)d_out;

    scores_kernel<<<B_, 256, 0, stream>>>(x, W, b, u, scores, sums);
    pool_kernel  <<<B_, 256, 0, stream>>>(x, scores, sums, out);
}

// Round 2
// 275.358 us; speedup vs baseline: 7.6955x; 7.6955x over previous
//
#include <hip/hip_runtime.h>
#include <math.h>

#define B_  256
#define T_  512
#define D_  256
#define A_  50
#define AP  52      // A padded to multiple of 4 (row stride 208 B = 16B-aligned)
#define EPS 1e-7f

// ---------------------------------------------------------------------------
// Prep: zero-pad W [D,50] -> W_pad [D,52] so every row is 16B-aligned and
// float4 loads never cross rows.
// ---------------------------------------------------------------------------
__global__ void pad_w_kernel(const float* __restrict__ W, float* __restrict__ Wp)
{
    int idx = blockIdx.x * 256 + threadIdx.x;
    if (idx >= D_ * AP) return;
    int d = idx / AP;
    int a = idx - d * AP;
    Wp[idx] = (a < A_) ? W[d * A_ + a] : 0.0f;
}

// ---------------------------------------------------------------------------
// Kernel 1: s[r] = exp( sum_a tanh( x[r,:]·Wp[:,a] + b[a] ) * u[a] )
// One row per thread. 512 blocks x 256 threads. acc[52] stays in VGPRs
// (~90 VGPR total -> no spill, 4 waves/SIMD). W/bias/u are read with
// wave-uniform addresses -> scalar (constant-cache) loads, zero LDS traffic
// in the hot loop. Block-reduces exp-scores into partial[block].
// ---------------------------------------------------------------------------
__global__ __launch_bounds__(256)
void scores_kernel(const float* __restrict__ x, const float* __restrict__ Wp,
                   const float* __restrict__ bias, const float* __restrict__ u,
                   float* __restrict__ s_out, float* __restrict__ partial)
{
    const int tid = threadIdx.x;
    const int r   = blockIdx.x * 256 + tid;   // global row in [0, B*T)
    const float4* __restrict__ xr4 = (const float4*)(x + (size_t)r * D_);

    float acc[AP];
    #pragma unroll
    for (int a = 0; a < AP; a++) acc[a] = 0.0f;

    for (int d4 = 0; d4 < D_ / 4; d4++) {
        const float4 xv = xr4[d4];
        #pragma unroll
        for (int j = 0; j < 4; j++) {
            const float xj = (j == 0) ? xv.x : (j == 1) ? xv.y : (j == 2) ? xv.z : xv.w;
            const float4* __restrict__ wrow =
                (const float4*)(Wp + (size_t)(d4 * 4 + j) * AP);
            #pragma unroll
            for (int a4 = 0; a4 < AP / 4; a4++) {
                const float4 w = wrow[a4];   // wave-uniform address -> s_load
                acc[4 * a4 + 0] += xj * w.x;
                acc[4 * a4 + 1] += xj * w.y;
                acc[4 * a4 + 2] += xj * w.z;
                acc[4 * a4 + 3] += xj * w.w;
            }
        }
    }

    float sc = 0.0f;
    #pragma unroll
    for (int a = 0; a < A_; a++)
        sc += tanhf(acc[a] + bias[a]) * u[a];   // bias/u: uniform scalar loads
    const float s = expf(sc);
    s_out[r] = s;

    // block-reduce sum of exp scores -> partial[blockIdx.x]
    __shared__ float red[256];
    red[tid] = s;
    __syncthreads();
    for (int off = 128; off > 0; off >>= 1) {
        if (tid < off) red[tid] += red[tid + off];
        __syncthreads();
    }
    if (tid == 0) partial[blockIdx.x] = red[0];
}

// ---------------------------------------------------------------------------
// Kernel 2: out[b,d] = sum_t x[b,t,d] * s[b,t] / (partial[2b]+partial[2b+1]+EPS)
// One block per batch. Wave w handles t in [w*128,(w+1)*128); lane l owns
// float4 d-chunk l (64 lanes * 4 = 256 = D). Perfectly coalesced 1KB/wave
// global loads. Cross-wave combine through LDS.
// ---------------------------------------------------------------------------
__global__ __launch_bounds__(256)
void pool_kernel(const float* __restrict__ x, const float* __restrict__ s_in,
                 const float* __restrict__ partial, float* __restrict__ out)
{
    __shared__ float s_lds[T_];
    __shared__ float part[4 * 256];

    const int tid = threadIdx.x;
    const int bb  = blockIdx.x;

    const float inv = 1.0f / (partial[2 * bb] + partial[2 * bb + 1] + EPS);
    s_lds[tid]       = s_in[(size_t)bb * T_ + tid]       * inv;
    s_lds[tid + 256] = s_in[(size_t)bb * T_ + 256 + tid] * inv;
    __syncthreads();

    const int w = tid >> 6;   // wave id 0..3
    const int l = tid & 63;   // lane

    const float* __restrict__ xb = x + (size_t)bb * T_ * D_;
    float4 acc = make_float4(0.f, 0.f, 0.f, 0.f);

    const int t0 = w * (T_ / 4);
    #pragma unroll 4
    for (int t = t0; t < t0 + T_ / 4; t++) {
        float4 xv = *(const float4*)(xb + (size_t)t * D_ + l * 4);
        float sv  = s_lds[t];
        acc.x += xv.x * sv;
        acc.y += xv.y * sv;
        acc.z += xv.z * sv;
        acc.w += xv.w * sv;
    }

    part[w * 256 + l * 4 + 0] = acc.x;
    part[w * 256 + l * 4 + 1] = acc.y;
    part[w * 256 + l * 4 + 2] = acc.z;
    part[w * 256 + l * 4 + 3] = acc.w;
    __syncthreads();

    float o = part[tid] + part[256 + tid] + part[512 + tid] + part[768 + tid];
    out[(size_t)bb * D_ + tid] = o;
}

// ---------------------------------------------------------------------------
extern "C" void kernel_launch(void* const* d_in, const int* in_sizes, int n_in,
                              void* d_out, int out_size, void* d_ws, size_t ws_size,
                              hipStream_t stream)
{
    const float* x = (const float*)d_in[0];
    const float* W = (const float*)d_in[1];
    const float* b = (const float*)d_in[2];
    const float* u = (const float*)d_in[3];

    float* scores  = (float*)d_ws;                      // B*T floats
    float* partial = scores + (size_t)B_ * T_;          // 512 floats
    float* Wp      = partial + 512;                     // D*AP floats
    float* out     = (float*)d_out;

    pad_w_kernel <<<(D_ * AP + 255) / 256, 256, 0, stream>>>(W, Wp);
    scores_kernel<<<(B_ * T_) / 256, 256, 0, stream>>>(x, Wp, b, u, scores, partial);
    pool_kernel  <<<B_, 256, 0, stream>>>(x, scores, partial, out);
}